// Round 13
// baseline (249.442 us; speedup 1.0000x reference)
//
#include <hip/hip_runtime.h>

#define N_NODES   50000
#define N_EDGES   800000
#define IN_DIM    89
#define KP1       96      // IN_DIM padded to multiple of 32
#define HID       128
#define N_CLASSES 64
#define N_GRAPHS  64
#define PSPLIT    16      // pool partial splits per graph

typedef __attribute__((ext_vector_type(8))) short bf16x8;
typedef __attribute__((ext_vector_type(4))) float f32x4;

__device__ __forceinline__ unsigned short f2bf(float x) {
    union { float f; unsigned u; } v; v.f = x;
    unsigned r = v.u + 0x7FFF + ((v.u >> 16) & 1);   // RTNE
    return (unsigned short)(r >> 16);
}
__device__ __forceinline__ float bf2f(unsigned short x) {
    union { unsigned u; float f; } v; v.u = ((unsigned)x) << 16;
    return v.f;
}

// Panel layout: Pp[p][node][32] bf16, p = dim/32 (4 panels x 3.2 MB)
__device__ __forceinline__ size_t pidx(int panel, int node, int off) {
    return ((size_t)panel * N_NODES + node) * 32 + off;
}

// ---------------------------------------------------------------------------
// MERGED prep + layer-1 GEMM (independent block branches, one dispatch):
//   blocks [0, NB_ROW):        rowptr binary search
//   blocks [NB_ROW, NB_PRE):   wt2 / wt3 transpose+bf16
//   blocks [NB_PRE, +782):     P1 = bf16(nf) @ W1 (W1 staged in LDS), panel out
// ---------------------------------------------------------------------------
#define NB_ROW  196
#define NB_WT2  128
#define NB_PRE  (NB_ROW + NB_WT2)          // 324
#define GEMM1_GRID ((N_NODES + 63) / 64)   // 782
#define WS1 100

__global__ __launch_bounds__(256) void prep_gemm1_kernel(
        const int* __restrict__ dst,
        const int* __restrict__ gid,
        const float* __restrict__ W1,
        const float* __restrict__ W2,
        const float* __restrict__ W3,
        const float* __restrict__ nf,
        int* __restrict__ node_ptr,
        int* __restrict__ graph_ptr,
        unsigned short* __restrict__ wt2,
        unsigned short* __restrict__ wt3,
        unsigned short* __restrict__ Y) {      // panel layout
    __shared__ unsigned short wt1s[HID * WS1];

    const int b = blockIdx.x;
    if (b < NB_ROW) {
        const int i = b * 256 + threadIdx.x;
        if (i <= N_NODES) {
            int lo = 0, hi = N_EDGES;
            while (lo < hi) { int mid = (lo + hi) >> 1; if (dst[mid] < i) lo = mid + 1; else hi = mid; }
            node_ptr[i] = lo;
        }
        if (i <= N_GRAPHS) {
            int lo = 0, hi = N_NODES;
            while (lo < hi) { int mid = (lo + hi) >> 1; if (gid[mid] < i) lo = mid + 1; else hi = mid; }
            graph_ptr[i] = lo;
        }
        return;
    }
    if (b < NB_PRE) {
        int idx = (b - NB_ROW) * 256 + threadIdx.x;
        if (idx < HID * HID) {
            const int col = idx / HID, k = idx - col * HID;
            wt2[idx] = f2bf(W2[(size_t)k * HID + col]);
        } else {
            idx -= HID * HID;
            const int col = idx / HID, k = idx - col * HID;
            wt3[idx] = f2bf(W3[(size_t)k * HID + col]);
        }
        return;
    }

    // ---- gemm1 branch ----
    const int tid = threadIdx.x;
    for (int idx = tid; idx < KP1 * HID; idx += 256) {
        const int k = idx >> 7, col = idx & 127;
        const float v = (k < IN_DIM) ? W1[(size_t)k * HID + col] : 0.f;
        wt1s[col * WS1 + k] = f2bf(v);
    }
    __syncthreads();

    const int wave = tid >> 6;
    const int lane = tid & 63;
    const int r    = lane & 15;
    const int kg   = lane >> 4;

    const int row  = (b - NB_PRE) * 64 + wave * 16 + r;
    const int rowc = (row < N_NODES) ? row : (N_NODES - 1);

    bf16x8 afrag[3];
#pragma unroll
    for (int t = 0; t < 3; ++t) {
        const int kb = 32 * t + kg * 8;
#pragma unroll
        for (int j = 0; j < 8; ++j) {
            const int k = kb + j;
            const float v = (k < IN_DIM) ? nf[(size_t)rowc * IN_DIM + k] : 0.f;
            afrag[t][j] = (short)f2bf(v);
        }
    }

    f32x4 acc[8];
#pragma unroll
    for (int i = 0; i < 8; ++i) acc[i] = (f32x4){0.f, 0.f, 0.f, 0.f};

#pragma unroll
    for (int t = 0; t < 3; ++t) {
#pragma unroll
        for (int c = 0; c < 8; ++c) {
            const bf16x8 bb = *reinterpret_cast<const bf16x8*>(
                &wt1s[(c * 16 + r) * WS1 + kg * 8 + 32 * t]);
            acc[c] = __builtin_amdgcn_mfma_f32_16x16x32_bf16(afrag[t], bb, acc[c], 0, 0, 0);
        }
    }

    const int orow0 = (b - NB_PRE) * 64 + wave * 16 + kg * 4;
#pragma unroll
    for (int c = 0; c < 8; ++c) {
        const int col = c * 16 + r;
        const int pan = col >> 5, off = col & 31;
#pragma unroll
        for (int p = 0; p < 4; ++p) {
            const int orow = orow0 + p;
            if (orow < N_NODES) Y[pidx(pan, orow, off)] = f2bf(acc[c][p]);
        }
    }
}

// ---------------------------------------------------------------------------
// Panel-partitioned mean aggregation + bias + ReLU.
// Block b: panel = b & 3 (all blocks with same b%8 land on one XCD ->
// the 3.2 MB panel stays L2-resident). 4 waves x 4 nodes/wave.
// lane = 16*nq + 4*es + dq: node-quarter, edge-slot, dim-quarter(8 dims,16B).
// One panel row = one 64-B cache line (4 lanes). Reduce across es: 2 shfl.
// OUT_F32: fp32 (layer 3, feeds pool); else bf16 [v][128] (feeds next GEMM).
// ---------------------------------------------------------------------------
template <bool OUT_F32>
__global__ __launch_bounds__(256) void agg_panel_kernel(
        const unsigned short* __restrict__ Pp,  // [4][N][32]
        const int* __restrict__ src,
        const int* __restrict__ node_ptr,
        const float* __restrict__ bias,
        void* __restrict__ outp) {
    const int b     = blockIdx.x;               // 12500 exact
    const int panel = b & 3;
    const int nb    = ((b >> 3) << 1) + ((b & 7) >> 2);   // 0..3124

    const int wave = threadIdx.x >> 6;
    const int lane = threadIdx.x & 63;
    const int nq = lane >> 4;
    const int es = (lane >> 2) & 3;
    const int dq = lane & 3;

    const int v  = nb * 16 + wave * 4 + nq;
    const int lo = node_ptr[v];
    const int hi = node_ptr[v + 1];
    const float inv = 1.0f / (float)max(hi - lo, 1);
    const int last = (hi > lo) ? (hi - 1) : 0;

    const unsigned short* base = Pp + (size_t)panel * N_NODES * 32 + dq * 8;

    float acc[8];
#pragma unroll
    for (int j = 0; j < 8; ++j) acc[j] = 0.f;

    int e = lo + es;
    for (; e + 12 < hi; e += 16) {              // 4 rows in flight, all valid
        const int u0 = __builtin_nontemporal_load(src + e);
        const int u1 = __builtin_nontemporal_load(src + e + 4);
        const int u2 = __builtin_nontemporal_load(src + e + 8);
        const int u3 = __builtin_nontemporal_load(src + e + 12);
        const bf16x8 r0 = *reinterpret_cast<const bf16x8*>(base + (size_t)u0 * 32);
        const bf16x8 r1 = *reinterpret_cast<const bf16x8*>(base + (size_t)u1 * 32);
        const bf16x8 r2 = *reinterpret_cast<const bf16x8*>(base + (size_t)u2 * 32);
        const bf16x8 r3 = *reinterpret_cast<const bf16x8*>(base + (size_t)u3 * 32);
#pragma unroll
        for (int j = 0; j < 8; ++j)
            acc[j] += (bf2f((unsigned short)r0[j]) + bf2f((unsigned short)r1[j]))
                    + (bf2f((unsigned short)r2[j]) + bf2f((unsigned short)r3[j]));
    }
    for (; e < hi; e += 4) {
        const int u = __builtin_nontemporal_load(src + min(e, last));
        const bf16x8 r = *reinterpret_cast<const bf16x8*>(base + (size_t)u * 32);
#pragma unroll
        for (int j = 0; j < 8; ++j) acc[j] += bf2f((unsigned short)r[j]);
    }

    // reduce across the 4 edge-slots
#pragma unroll
    for (int j = 0; j < 8; ++j) {
        acc[j] += __shfl_xor(acc[j], 4);
        acc[j] += __shfl_xor(acc[j], 8);
    }

    if (es == 0) {
        const int d0 = panel * 32 + dq * 8;
        const float4 b0 = *reinterpret_cast<const float4*>(bias + d0);
        const float4 b1 = *reinterpret_cast<const float4*>(bias + d0 + 4);
        float o[8];
        o[0] = fmaxf(acc[0] * inv + b0.x, 0.f);
        o[1] = fmaxf(acc[1] * inv + b0.y, 0.f);
        o[2] = fmaxf(acc[2] * inv + b0.z, 0.f);
        o[3] = fmaxf(acc[3] * inv + b0.w, 0.f);
        o[4] = fmaxf(acc[4] * inv + b1.x, 0.f);
        o[5] = fmaxf(acc[5] * inv + b1.y, 0.f);
        o[6] = fmaxf(acc[6] * inv + b1.z, 0.f);
        o[7] = fmaxf(acc[7] * inv + b1.w, 0.f);
        if (OUT_F32) {
            float* op = (float*)outp + (size_t)v * HID + d0;
            *reinterpret_cast<float4*>(op)     = make_float4(o[0], o[1], o[2], o[3]);
            *reinterpret_cast<float4*>(op + 4) = make_float4(o[4], o[5], o[6], o[7]);
        } else {
            bf16x8 ob;
#pragma unroll
            for (int j = 0; j < 8; ++j) ob[j] = (short)f2bf(o[j]);
            *reinterpret_cast<bf16x8*>((unsigned short*)outp + (size_t)v * HID + d0) = ob;
        }
    }
}

// ---------------------------------------------------------------------------
// MFMA GEMM: Ypanels = X[M x 128](bf16) @ W (via WT[128][128] bf16).
// Block = 4 waves; wave = 16 rows x 128 cols. No LDS. Panel-layout output.
// ---------------------------------------------------------------------------
__global__ __launch_bounds__(256) void mfma_gemm_kernel(
        const unsigned short* __restrict__ Xb,   // [M][128]
        const unsigned short* __restrict__ WT,   // [128][128]
        unsigned short* __restrict__ Y) {        // panel layout
    const int wave = threadIdx.x >> 6;
    const int lane = threadIdx.x & 63;
    const int r    = lane & 15;
    const int kg   = lane >> 4;

    const int row  = blockIdx.x * 64 + wave * 16 + r;
    const int rowc = (row < N_NODES) ? row : (N_NODES - 1);

    f32x4 acc[8];
#pragma unroll
    for (int i = 0; i < 8; ++i) acc[i] = (f32x4){0.f, 0.f, 0.f, 0.f};

    const unsigned short* xrow = Xb + (size_t)rowc * HID + kg * 8;

#pragma unroll
    for (int k0 = 0; k0 < HID; k0 += 32) {
        const bf16x8 a = *reinterpret_cast<const bf16x8*>(xrow + k0);
#pragma unroll
        for (int c = 0; c < 8; ++c) {
            const bf16x8 bb = *reinterpret_cast<const bf16x8*>(
                WT + (size_t)(c * 16 + r) * HID + kg * 8 + k0);
            acc[c] = __builtin_amdgcn_mfma_f32_16x16x32_bf16(a, bb, acc[c], 0, 0, 0);
        }
    }

    const int orow0 = blockIdx.x * 64 + wave * 16 + kg * 4;
#pragma unroll
    for (int c = 0; c < 8; ++c) {
        const int col = c * 16 + r;
        const int pan = col >> 5, off = col & 31;
#pragma unroll
        for (int p = 0; p < 4; ++p) {
            const int orow = orow0 + p;
            if (orow < N_NODES) Y[pidx(pan, orow, off)] = f2bf(acc[c][p]);
        }
    }
}

// ---------------------------------------------------------------------------
// Pool stage A: 1024 blocks (64 graphs x 16 splits), unscaled partial sums.
// ---------------------------------------------------------------------------
__global__ void pool_partial_kernel(const float* __restrict__ h3,
                                    const int* __restrict__ graph_ptr,
                                    float* __restrict__ hgp) {
    const int g   = blockIdx.x / PSPLIT;
    const int s   = blockIdx.x % PSPLIT;
    const int j   = threadIdx.x;                // 128
    const int lo  = graph_ptr[g];
    const int hi  = graph_ptr[g + 1];

    float acc = 0.f;
    for (int r = lo + s; r < hi; r += PSPLIT)
        acc += h3[(size_t)r * HID + j];
    hgp[(size_t)blockIdx.x * HID + j] = acc;
}

// ---------------------------------------------------------------------------
// Pool stage B + classifier: block per graph.
// ---------------------------------------------------------------------------
__global__ void cls_kernel(const float* __restrict__ hgp,
                           const int* __restrict__ graph_ptr,
                           const float* __restrict__ Wc1,
                           const float* __restrict__ bc1,
                           const float* __restrict__ Wc2,
                           const float* __restrict__ bc2,
                           float* __restrict__ out) {
    const int g = blockIdx.x;                   // 64
    const int j = threadIdx.x;                  // 128
    const int cnt = graph_ptr[g + 1] - graph_ptr[g];
    const float inv = 1.0f / (float)max(cnt, 1);

    float acc = 0.f;
#pragma unroll
    for (int s = 0; s < PSPLIT; ++s)
        acc += hgp[(size_t)(g * PSPLIT + s) * HID + j];

    __shared__ float row[HID];
    __shared__ float trow[HID];
    row[j] = acc * inv;
    __syncthreads();

    float a1 = bc1[j];
#pragma unroll 4
    for (int k = 0; k < HID; ++k) a1 = fmaf(row[k], Wc1[k * HID + j], a1);
    trow[j] = fmaxf(a1, 0.f);
    __syncthreads();

    if (j < N_CLASSES) {
        float a2 = bc2[j];
#pragma unroll 4
        for (int k = 0; k < HID; ++k) a2 = fmaf(trow[k], Wc2[k * N_CLASSES + j], a2);
        out[g * N_CLASSES + j] = a2;
    }
}

// ---------------------------------------------------------------------------
extern "C" void kernel_launch(void* const* d_in, const int* in_sizes, int n_in,
                              void* d_out, int out_size, void* d_ws, size_t ws_size,
                              hipStream_t stream) {
    const float* nf   = (const float*)d_in[0];
    const int*   src  = (const int*)  d_in[1];
    const int*   dst  = (const int*)  d_in[2];
    const int*   gid  = (const int*)  d_in[3];
    const float* W1  = (const float*)d_in[5];
    const float* b1  = (const float*)d_in[6];
    const float* W2  = (const float*)d_in[7];
    const float* b2  = (const float*)d_in[8];
    const float* W3  = (const float*)d_in[9];
    const float* b3  = (const float*)d_in[10];
    const float* Wc1 = (const float*)d_in[11];
    const float* bc1 = (const float*)d_in[12];
    const float* Wc2 = (const float*)d_in[13];
    const float* bc2 = (const float*)d_in[14];
    float* out = (float*)d_out;

    char* ws = (char*)d_ws;
    size_t off = 0;
    auto alloc = [&](size_t bytes) { void* p = ws + off; off = (off + bytes + 255) & ~(size_t)255; return p; };
    int*   node_ptr  = (int*)  alloc((N_NODES + 1) * sizeof(int));
    int*   graph_ptr = (int*)  alloc((N_GRAPHS + 1) * sizeof(int));
    float* h3        = (float*)alloc((size_t)N_NODES * HID * sizeof(float));
    unsigned short* PbA = (unsigned short*)alloc((size_t)N_NODES * HID * sizeof(unsigned short)); // panels
    unsigned short* hb  = (unsigned short*)alloc((size_t)N_NODES * HID * sizeof(unsigned short)); // h linear
    unsigned short* wt2 = (unsigned short*)alloc((size_t)HID * HID * sizeof(unsigned short));
    unsigned short* wt3 = (unsigned short*)alloc((size_t)HID * HID * sizeof(unsigned short));
    float* hgp       = (float*)alloc((size_t)N_GRAPHS * PSPLIT * HID * sizeof(float));
    (void)ws_size;

    const int AGG_GRID  = 12500;                 // 4 panels x 3125 node-groups
    const int GEMM_GRID = (N_NODES + 63) / 64;   // 782

    // 1. merged prep + gemm1 (P1 panels)
    prep_gemm1_kernel<<<NB_PRE + GEMM1_GRID, 256, 0, stream>>>(
        dst, gid, W1, W2, W3, nf, node_ptr, graph_ptr, wt2, wt3, PbA);

    // 2. h1 = relu(agg(P1)+b1)            (panel gather, linear bf16 out)
    agg_panel_kernel<false><<<AGG_GRID, 256, 0, stream>>>(PbA, src, node_ptr, b1, hb);

    // 3. P2 = h1 @ W2  (panels)
    mfma_gemm_kernel<<<GEMM_GRID, 256, 0, stream>>>(hb, wt2, PbA);

    // 4. h2 = relu(agg(P2)+b2)
    agg_panel_kernel<false><<<AGG_GRID, 256, 0, stream>>>(PbA, src, node_ptr, b2, hb);

    // 5. P3 = h2 @ W3  (panels)
    mfma_gemm_kernel<<<GEMM_GRID, 256, 0, stream>>>(hb, wt3, PbA);

    // 6. h3 = relu(agg(P3)+b3)  (fp32 linear, feeds pool)
    agg_panel_kernel<true><<<AGG_GRID, 256, 0, stream>>>(PbA, src, node_ptr, b3, h3);

    // 7. pool partials (wide), 8. reduce + classifier
    pool_partial_kernel<<<N_GRAPHS * PSPLIT, HID, 0, stream>>>(h3, graph_ptr, hgp);
    cls_kernel<<<N_GRAPHS, HID, 0, stream>>>(hgp, graph_ptr, Wc1, bc1, Wc2, bc2, out);
}

// Round 14
// 171.638 us; speedup vs baseline: 1.4533x; 1.4533x over previous
//
#include <hip/hip_runtime.h>

#define N_NODES   50000
#define N_EDGES   800000
#define IN_DIM    89
#define KP1       96      // IN_DIM padded to multiple of 32
#define HID       128
#define N_CLASSES 64
#define N_GRAPHS  64
#define PSPLIT    16      // pool partial splits per graph

typedef __attribute__((ext_vector_type(8))) short bf16x8;
typedef __attribute__((ext_vector_type(4))) float f32x4;

__device__ __forceinline__ unsigned short f2bf(float x) {
    union { float f; unsigned u; } v; v.f = x;
    unsigned r = v.u + 0x7FFF + ((v.u >> 16) & 1);   // RTNE
    return (unsigned short)(r >> 16);
}
__device__ __forceinline__ float bf2f(unsigned short x) {
    union { unsigned u; float f; } v; v.u = ((unsigned)x) << 16;
    return v.f;
}

// ---------------------------------------------------------------------------
// MERGED prep + layer-1 GEMM (independent block branches, one dispatch):
//   blocks [0, NB_ROW):        rowptr binary search (node_ptr, graph_ptr)
//   blocks [NB_ROW, NB_PRE):   wt2 / wt3 transpose+bf16
//   blocks [NB_PRE, +782):     P1 = bf16(nf) @ W1, W1 staged per-block in LDS
// ---------------------------------------------------------------------------
#define NB_ROW  196                        // ceil(50001/256)
#define NB_WT2  128                        // 2*128*128/256
#define NB_PRE  (NB_ROW + NB_WT2)          // 324
#define GEMM1_GRID ((N_NODES + 63) / 64)   // 782
#define WS1 100                            // padded k-stride for W1 LDS tile

__global__ __launch_bounds__(256) void prep_gemm1_kernel(
        const int* __restrict__ dst,
        const int* __restrict__ gid,
        const float* __restrict__ W1,
        const float* __restrict__ W2,
        const float* __restrict__ W3,
        const float* __restrict__ nf,
        int* __restrict__ node_ptr,
        int* __restrict__ graph_ptr,
        unsigned short* __restrict__ wt2,
        unsigned short* __restrict__ wt3,
        unsigned short* __restrict__ Y) {
    __shared__ unsigned short wt1s[HID * WS1];   // [col][k], 25.6 KB

    const int b = blockIdx.x;
    if (b < NB_ROW) {
        const int i = b * 256 + threadIdx.x;
        if (i <= N_NODES) {
            int lo = 0, hi = N_EDGES;
            while (lo < hi) { int mid = (lo + hi) >> 1; if (dst[mid] < i) lo = mid + 1; else hi = mid; }
            node_ptr[i] = lo;
        }
        if (i <= N_GRAPHS) {
            int lo = 0, hi = N_NODES;
            while (lo < hi) { int mid = (lo + hi) >> 1; if (gid[mid] < i) lo = mid + 1; else hi = mid; }
            graph_ptr[i] = lo;
        }
        return;
    }
    if (b < NB_PRE) {
        int idx = (b - NB_ROW) * 256 + threadIdx.x;
        if (idx < HID * HID) {
            const int col = idx / HID, k = idx - col * HID;
            wt2[idx] = f2bf(W2[(size_t)k * HID + col]);
        } else {
            idx -= HID * HID;
            const int col = idx / HID, k = idx - col * HID;
            wt3[idx] = f2bf(W3[(size_t)k * HID + col]);
        }
        return;
    }

    // ---- gemm1 branch ----
    const int tid = threadIdx.x;
    for (int idx = tid; idx < KP1 * HID; idx += 256) {
        const int k = idx >> 7, col = idx & 127;
        const float v = (k < IN_DIM) ? W1[(size_t)k * HID + col] : 0.f;
        wt1s[col * WS1 + k] = f2bf(v);
    }
    __syncthreads();

    const int wave = tid >> 6;
    const int lane = tid & 63;
    const int r    = lane & 15;
    const int kg   = lane >> 4;

    const int row  = (b - NB_PRE) * 64 + wave * 16 + r;
    const int rowc = (row < N_NODES) ? row : (N_NODES - 1);

    bf16x8 afrag[3];
#pragma unroll
    for (int t = 0; t < 3; ++t) {
        const int kb = 32 * t + kg * 8;
#pragma unroll
        for (int j = 0; j < 8; ++j) {
            const int k = kb + j;
            const float v = (k < IN_DIM) ? nf[(size_t)rowc * IN_DIM + k] : 0.f;
            afrag[t][j] = (short)f2bf(v);
        }
    }

    f32x4 acc[8];
#pragma unroll
    for (int i = 0; i < 8; ++i) acc[i] = (f32x4){0.f, 0.f, 0.f, 0.f};

#pragma unroll
    for (int t = 0; t < 3; ++t) {
#pragma unroll
        for (int c = 0; c < 8; ++c) {
            const bf16x8 bb = *reinterpret_cast<const bf16x8*>(
                &wt1s[(c * 16 + r) * WS1 + kg * 8 + 32 * t]);
            acc[c] = __builtin_amdgcn_mfma_f32_16x16x32_bf16(afrag[t], bb, acc[c], 0, 0, 0);
        }
    }

    const int orow0 = (b - NB_PRE) * 64 + wave * 16 + kg * 4;
#pragma unroll
    for (int c = 0; c < 8; ++c)
#pragma unroll
        for (int p = 0; p < 4; ++p) {
            const int orow = orow0 + p;
            if (orow < N_NODES) Y[(size_t)orow * HID + c * 16 + r] = f2bf(acc[c][p]);
        }
}

// ---------------------------------------------------------------------------
// FUSED agg + GEMM (r8-proven static form):
// Block = 16 nodes, 4 waves; wave statically aggregates 4 nodes into the
// shared 16x128 LDS tile (2x-unrolled gather), syncthreads, then wave w
// computes nf-tiles {2w, 2w+1} (8 MFMAs). Grid = 3125 (50000 = 3125*16).
// ---------------------------------------------------------------------------
__global__ __launch_bounds__(256) void fused_agg_gemm_kernel(
        const unsigned short* __restrict__ Pin,
        const int* __restrict__ src,
        const int* __restrict__ node_ptr,
        const float* __restrict__ bias,
        const unsigned short* __restrict__ WT,
        unsigned short* __restrict__ Pout) {
    __shared__ unsigned short hs[16][136];      // 16 x 128 (+8 pad)

    const int wave = threadIdx.x >> 6;
    const int lane = threadIdx.x & 63;
    const int q    = lane >> 4;                 // edge sub-slot 0..3
    const int g    = lane & 15;                 // dim group [8g, 8g+8)
    const int vbase = blockIdx.x * 16;

    const float4 b0 = *reinterpret_cast<const float4*>(bias + g * 8);
    const float4 b1 = *reinterpret_cast<const float4*>(bias + g * 8 + 4);

    // ---- phase 1: each wave aggregates 4 nodes ----
#pragma unroll
    for (int i = 0; i < 4; ++i) {
        const int li = wave * 4 + i;            // local row 0..15
        const int v  = vbase + li;
        const int lo = node_ptr[v];
        const int hi = node_ptr[v + 1];
        const float inv = 1.0f / (float)max(hi - lo, 1);

        float acc[8];
#pragma unroll
        for (int j = 0; j < 8; ++j) acc[j] = 0.f;

        int e = lo + q;
        for (; e + 4 < hi; e += 8) {            // 2 loads in flight
            const int u0 = src[e];
            const int u1 = src[e + 4];
            const bf16x8 r0 = *reinterpret_cast<const bf16x8*>(Pin + (size_t)u0 * HID + g * 8);
            const bf16x8 r1 = *reinterpret_cast<const bf16x8*>(Pin + (size_t)u1 * HID + g * 8);
#pragma unroll
            for (int j = 0; j < 8; ++j)
                acc[j] += bf2f((unsigned short)r0[j]) + bf2f((unsigned short)r1[j]);
        }
        if (e < hi) {
            const int u = src[e];
            const bf16x8 r = *reinterpret_cast<const bf16x8*>(Pin + (size_t)u * HID + g * 8);
#pragma unroll
            for (int j = 0; j < 8; ++j) acc[j] += bf2f((unsigned short)r[j]);
        }
#pragma unroll
        for (int j = 0; j < 8; ++j) {
            acc[j] += __shfl_xor(acc[j], 16);
            acc[j] += __shfl_xor(acc[j], 32);
        }
        if (q == 0) {
            bf16x8 ob;
            ob[0] = (short)f2bf(fmaxf(acc[0] * inv + b0.x, 0.f));
            ob[1] = (short)f2bf(fmaxf(acc[1] * inv + b0.y, 0.f));
            ob[2] = (short)f2bf(fmaxf(acc[2] * inv + b0.z, 0.f));
            ob[3] = (short)f2bf(fmaxf(acc[3] * inv + b0.w, 0.f));
            ob[4] = (short)f2bf(fmaxf(acc[4] * inv + b1.x, 0.f));
            ob[5] = (short)f2bf(fmaxf(acc[5] * inv + b1.y, 0.f));
            ob[6] = (short)f2bf(fmaxf(acc[6] * inv + b1.z, 0.f));
            ob[7] = (short)f2bf(fmaxf(acc[7] * inv + b1.w, 0.f));
            *reinterpret_cast<bf16x8*>(&hs[li][g * 8]) = ob;
        }
    }
    __syncthreads();

    // ---- phase 2: wave w computes nf-tiles {2w, 2w+1} ----
    const int r  = lane & 15;
    const int kg = lane >> 4;

    f32x4 acc2[2];
#pragma unroll
    for (int t = 0; t < 2; ++t) acc2[t] = (f32x4){0.f, 0.f, 0.f, 0.f};

#pragma unroll
    for (int k0 = 0; k0 < HID; k0 += 32) {
        const bf16x8 a = *reinterpret_cast<const bf16x8*>(&hs[r][kg * 8 + k0]);
#pragma unroll
        for (int t = 0; t < 2; ++t) {
            const int nf = wave * 2 + t;
            const bf16x8 b = *reinterpret_cast<const bf16x8*>(
                WT + (size_t)(nf * 16 + r) * HID + kg * 8 + k0);
            acc2[t] = __builtin_amdgcn_mfma_f32_16x16x32_bf16(a, b, acc2[t], 0, 0, 0);
        }
    }

    const int orow0 = vbase + kg * 4;
#pragma unroll
    for (int t = 0; t < 2; ++t) {
        const int nf = wave * 2 + t;
#pragma unroll
        for (int p = 0; p < 4; ++p)
            Pout[(size_t)(orow0 + p) * HID + nf * 16 + r] = f2bf(acc2[t][p]);
    }
}

// ---------------------------------------------------------------------------
// Final aggregation (layer 3): fp32 output for pooling. Wave-per-node.
// ---------------------------------------------------------------------------
__global__ void agg128_f32_kernel(const unsigned short* __restrict__ Pb,
                                  const int* __restrict__ src,
                                  const int* __restrict__ node_ptr,
                                  const float* __restrict__ bias,
                                  float* __restrict__ out) {
    const int wave = threadIdx.x >> 6;
    const int lane = threadIdx.x & 63;
    const int v    = blockIdx.x * 4 + wave;
    if (v >= N_NODES) return;

    const int lo = node_ptr[v];
    const int hi = node_ptr[v + 1];
    const float inv = 1.0f / (float)max(hi - lo, 1);

    const int q = lane >> 4;
    const int g = lane & 15;

    float acc[8];
#pragma unroll
    for (int j = 0; j < 8; ++j) acc[j] = 0.f;

    int e = lo + q;
    for (; e + 4 < hi; e += 8) {
        const int u0 = src[e];
        const int u1 = src[e + 4];
        const bf16x8 r0 = *reinterpret_cast<const bf16x8*>(Pb + (size_t)u0 * HID + g * 8);
        const bf16x8 r1 = *reinterpret_cast<const bf16x8*>(Pb + (size_t)u1 * HID + g * 8);
#pragma unroll
        for (int j = 0; j < 8; ++j)
            acc[j] += bf2f((unsigned short)r0[j]) + bf2f((unsigned short)r1[j]);
    }
    if (e < hi) {
        const int u = src[e];
        const bf16x8 r = *reinterpret_cast<const bf16x8*>(Pb + (size_t)u * HID + g * 8);
#pragma unroll
        for (int j = 0; j < 8; ++j) acc[j] += bf2f((unsigned short)r[j]);
    }
#pragma unroll
    for (int j = 0; j < 8; ++j) {
        acc[j] += __shfl_xor(acc[j], 16);
        acc[j] += __shfl_xor(acc[j], 32);
    }

    if (q == 0) {
        const float4 b0 = *reinterpret_cast<const float4*>(bias + g * 8);
        const float4 b1 = *reinterpret_cast<const float4*>(bias + g * 8 + 4);
        float4 a = make_float4(fmaxf(acc[0] * inv + b0.x, 0.f), fmaxf(acc[1] * inv + b0.y, 0.f),
                               fmaxf(acc[2] * inv + b0.z, 0.f), fmaxf(acc[3] * inv + b0.w, 0.f));
        float4 b = make_float4(fmaxf(acc[4] * inv + b1.x, 0.f), fmaxf(acc[5] * inv + b1.y, 0.f),
                               fmaxf(acc[6] * inv + b1.z, 0.f), fmaxf(acc[7] * inv + b1.w, 0.f));
        *reinterpret_cast<float4*>(out + (size_t)v * HID + g * 8)     = a;
        *reinterpret_cast<float4*>(out + (size_t)v * HID + g * 8 + 4) = b;
    }
}

// ---------------------------------------------------------------------------
// Pool stage A: 1024 blocks (64 graphs x 16 splits), unscaled partial sums.
// ---------------------------------------------------------------------------
__global__ void pool_partial_kernel(const float* __restrict__ h3,
                                    const int* __restrict__ graph_ptr,
                                    float* __restrict__ hgp) {
    const int g   = blockIdx.x / PSPLIT;
    const int s   = blockIdx.x % PSPLIT;
    const int j   = threadIdx.x;                // 128
    const int lo  = graph_ptr[g];
    const int hi  = graph_ptr[g + 1];

    float acc = 0.f;
    for (int r = lo + s; r < hi; r += PSPLIT)
        acc += h3[(size_t)r * HID + j];
    hgp[(size_t)blockIdx.x * HID + j] = acc;
}

// ---------------------------------------------------------------------------
// Pool stage B + classifier: block per graph.
// ---------------------------------------------------------------------------
__global__ void cls_kernel(const float* __restrict__ hgp,
                           const int* __restrict__ graph_ptr,
                           const float* __restrict__ Wc1,
                           const float* __restrict__ bc1,
                           const float* __restrict__ Wc2,
                           const float* __restrict__ bc2,
                           float* __restrict__ out) {
    const int g = blockIdx.x;                   // 64
    const int j = threadIdx.x;                  // 128
    const int cnt = graph_ptr[g + 1] - graph_ptr[g];
    const float inv = 1.0f / (float)max(cnt, 1);

    float acc = 0.f;
#pragma unroll
    for (int s = 0; s < PSPLIT; ++s)
        acc += hgp[(size_t)(g * PSPLIT + s) * HID + j];

    __shared__ float row[HID];
    __shared__ float trow[HID];
    row[j] = acc * inv;
    __syncthreads();

    float a1 = bc1[j];
#pragma unroll 4
    for (int k = 0; k < HID; ++k) a1 = fmaf(row[k], Wc1[k * HID + j], a1);
    trow[j] = fmaxf(a1, 0.f);
    __syncthreads();

    if (j < N_CLASSES) {
        float a2 = bc2[j];
#pragma unroll 4
        for (int k = 0; k < HID; ++k) a2 = fmaf(trow[k], Wc2[k * N_CLASSES + j], a2);
        out[g * N_CLASSES + j] = a2;
    }
}

// ---------------------------------------------------------------------------
extern "C" void kernel_launch(void* const* d_in, const int* in_sizes, int n_in,
                              void* d_out, int out_size, void* d_ws, size_t ws_size,
                              hipStream_t stream) {
    const float* nf   = (const float*)d_in[0];
    const int*   src  = (const int*)  d_in[1];
    const int*   dst  = (const int*)  d_in[2];
    const int*   gid  = (const int*)  d_in[3];
    const float* W1  = (const float*)d_in[5];
    const float* b1  = (const float*)d_in[6];
    const float* W2  = (const float*)d_in[7];
    const float* b2  = (const float*)d_in[8];
    const float* W3  = (const float*)d_in[9];
    const float* b3  = (const float*)d_in[10];
    const float* Wc1 = (const float*)d_in[11];
    const float* bc1 = (const float*)d_in[12];
    const float* Wc2 = (const float*)d_in[13];
    const float* bc2 = (const float*)d_in[14];
    float* out = (float*)d_out;

    char* ws = (char*)d_ws;
    size_t off = 0;
    auto alloc = [&](size_t bytes) { void* p = ws + off; off = (off + bytes + 255) & ~(size_t)255; return p; };
    int*   node_ptr  = (int*)  alloc((N_NODES + 1) * sizeof(int));
    int*   graph_ptr = (int*)  alloc((N_GRAPHS + 1) * sizeof(int));
    float* h3        = (float*)alloc((size_t)N_NODES * HID * sizeof(float));
    unsigned short* PbA = (unsigned short*)alloc((size_t)N_NODES * HID * sizeof(unsigned short));
    unsigned short* PbB = (unsigned short*)alloc((size_t)N_NODES * HID * sizeof(unsigned short));
    unsigned short* wt2 = (unsigned short*)alloc((size_t)HID * HID * sizeof(unsigned short));
    unsigned short* wt3 = (unsigned short*)alloc((size_t)HID * HID * sizeof(unsigned short));
    float* hgp       = (float*)alloc((size_t)N_GRAPHS * PSPLIT * HID * sizeof(float));
    (void)ws_size;

    const int FUSED_GRID = N_NODES / 16;          // 3125 (exact)
    const int AGG_GRID   = (N_NODES + 3) / 4;

    // 1. merged prep + gemm1
    prep_gemm1_kernel<<<NB_PRE + GEMM1_GRID, 256, 0, stream>>>(
        dst, gid, W1, W2, W3, nf, node_ptr, graph_ptr, wt2, wt3, PbA);

    // 2. h1 = relu(agg(P1)+b1); P2 = h1 @ W2
    fused_agg_gemm_kernel<<<FUSED_GRID, 256, 0, stream>>>(PbA, src, node_ptr, b1, wt2, PbB);

    // 3. h2 = relu(agg(P2)+b2); P3 = h2 @ W3
    fused_agg_gemm_kernel<<<FUSED_GRID, 256, 0, stream>>>(PbB, src, node_ptr, b2, wt3, PbA);

    // 4. h3 = relu(agg(P3)+b3)  (fp32)
    agg128_f32_kernel<<<AGG_GRID, 256, 0, stream>>>(PbA, src, node_ptr, b3, h3);

    // 5. pool partials (wide), 6. reduce + classifier
    pool_partial_kernel<<<N_GRAPHS * PSPLIT, HID, 0, stream>>>(h3, graph_ptr, hgp);
    cls_kernel<<<N_GRAPHS, HID, 0, stream>>>(hgp, graph_ptr, Wc1, bc1, Wc2, bc2, out);
}